// Round 14
// baseline (590.994 us; speedup 1.0000x reference)
//
#include <hip/hip_runtime.h>

#define KT 4
#define KN 20000        // NA == ND == 20000
#define KE 100000
#define KH 128
#define KL 2
#define KNT 40000       // NA + ND

typedef __attribute__((ext_vector_type(8))) short short8v;
typedef __attribute__((ext_vector_type(4))) float f32x4;

__device__ __forceinline__ short bf16rn(float x) {
    unsigned u = __float_as_uint(x);
    u = (u + 0x7fffu + ((u >> 16) & 1u)) >> 16;
    return (short)u;
}
__device__ __forceinline__ float bf16tof(short h) {
    return __uint_as_float(((unsigned)(unsigned short)h) << 16);
}
__device__ __forceinline__ short8v mk8(uint2 a, uint2 b) {
    union { unsigned u[4]; short8v s; } c;
    c.u[0] = a.x; c.u[1] = a.y; c.u[2] = b.x; c.u[3] = b.y;
    return c.s;
}

// ---------------------------------------------------------------------------
// CSR build: counts -> scan -> fill (packed (edge, src) pairs).  All 8 z.
// ---------------------------------------------------------------------------
__global__ void count_k(const int* __restrict__ ei_ad, const int* __restrict__ ei_da,
                        int* __restrict__ cnt) {
    int e = blockIdx.x * 256 + threadIdx.x;
    int z = blockIdx.y;                 // z = t*2 + et
    if (e >= KE) return;
    int t = z >> 1, et = z & 1;
    const int* ei = et ? ei_da : ei_ad;
    int dst = ei[(t * 2 + 1) * KE + e];
    atomicAdd(&cnt[z * KN + dst], 1);
}

__global__ void scan_k(int* __restrict__ cnt, int* __restrict__ offs) {
    __shared__ int s[256];
    int z = blockIdx.x, tid = threadIdx.x;
    const int CH = (KN + 255) / 256;    // 79
    int n0 = tid * CH;
    int lim = n0 < KN ? min(CH, KN - n0) : 0;
    long base = (long)z * KN + n0;
    int sum = 0;
    for (int i = 0; i < lim; ++i) sum += cnt[base + i];
    s[tid] = sum;
    __syncthreads();
    for (int off = 1; off < 256; off <<= 1) {
        int v = (tid >= off) ? s[tid - off] : 0;
        __syncthreads();
        s[tid] += v;
        __syncthreads();
    }
    int run = s[tid] - sum;             // exclusive prefix
    for (int i = 0; i < lim; ++i) {
        int c = cnt[base + i];
        offs[(long)z * (KN + 1) + n0 + i] = run;
        cnt[base + i] = run;            // becomes fill cursor
        run += c;
    }
    if (tid == 0) offs[(long)z * (KN + 1) + KN] = KE;
}

__global__ void fill_k(const int* __restrict__ ei_ad, const int* __restrict__ ei_da,
                       int* __restrict__ cur, int2* __restrict__ pes) {
    int e = blockIdx.x * 256 + threadIdx.x;
    int z = blockIdx.y;
    if (e >= KE) return;
    int t = z >> 1, et = z & 1;
    const int* ei = et ? ei_da : ei_ad;
    int src = ei[(t * 2 + 0) * KE + e];
    int dst = ei[(t * 2 + 1) * KE + e];
    int pos = atomicAdd(&cur[z * KN + dst], 1);
    pes[(long)z * KE + pos] = make_int2(e, src);
}

// ---------------------------------------------------------------------------
// Aggregation (per (t,l) launch, blockIdx.y = et): 32-lane group per node,
// 4-deep clamped fp32 row-gather batches.  Output SINGLE bf16 (exact MFMA
// input; W carries the hi/lo split).  Per-t scheduling keeps ea[t] (102 MB)
// L3-resident so the l=1 launch re-reads it from Infinity Cache.
// ---------------------------------------------------------------------------
__global__ __launch_bounds__(256)
void agg_k(const float* __restrict__ xa_base, long xa_ts,
           const float* __restrict__ xd_base, long xd_ts,
           const float* __restrict__ ea_ad, const float* __restrict__ ea_da,
           const float* __restrict__ eps_ad, const float* __restrict__ eps_da,
           const int* __restrict__ offs, const int2* __restrict__ pes,
           short* __restrict__ agg_b, int t, int l) {
    int et = blockIdx.y, z = t * 2 + et;
    int li = threadIdx.x & 31;
    int node = blockIdx.x * 8 + (threadIdx.x >> 5);   // grid exact: KN/8

    const float* ea  = (et ? ea_da : ea_ad) + (long)t * KE * KH;
    const float* eps = et ? eps_da : eps_ad;
    const float* src = et ? (xd_base + t * xd_ts) : (xa_base + t * xa_ts);
    const float* dst = et ? (xa_base + t * xa_ts) : (xd_base + t * xd_ts);
    const int2*  pz  = pes + (long)z * KE;

    int beg = offs[(long)z * (KN + 1) + node];
    int end = offs[(long)z * (KN + 1) + node + 1];
    float scale = 1.0f + eps[t * KL + l];

    float4 dv = *(const float4*)(dst + (long)node * KH + li * 4);
    float4 acc = make_float4(0.f, 0.f, 0.f, 0.f);

    if (beg < end) {
        int last = end - 1;
        for (int i = beg; i < end; i += 4) {
            int i0 = min(i, last), i1 = min(i + 1, last),
                i2 = min(i + 2, last), i3 = min(i + 3, last);
            int2 p0 = pz[i0], p1 = pz[i1], p2 = pz[i2], p3 = pz[i3];
            float4 e0 = *(const float4*)(ea + (long)p0.x * KH + li * 4);
            float4 e1 = *(const float4*)(ea + (long)p1.x * KH + li * 4);
            float4 e2 = *(const float4*)(ea + (long)p2.x * KH + li * 4);
            float4 e3 = *(const float4*)(ea + (long)p3.x * KH + li * 4);
            float4 x0 = *(const float4*)(src + (long)p0.y * KH + li * 4);
            float4 x1 = *(const float4*)(src + (long)p1.y * KH + li * 4);
            float4 x2 = *(const float4*)(src + (long)p2.y * KH + li * 4);
            float4 x3 = *(const float4*)(src + (long)p3.y * KH + li * 4);
            float4 es4[4] = {e0, e1, e2, e3};
            float4 xs[4] = {x0, x1, x2, x3};
            #pragma unroll
            for (int u = 0; u < 4; ++u) {
                float m = (i + u <= last) ? 1.0f : 0.0f;
                acc.x = fmaf(m, fmaxf(xs[u].x + es4[u].x, 0.f), acc.x);
                acc.y = fmaf(m, fmaxf(xs[u].y + es4[u].y, 0.f), acc.y);
                acc.z = fmaf(m, fmaxf(xs[u].z + es4[u].z, 0.f), acc.z);
                acc.w = fmaf(m, fmaxf(xs[u].w + es4[u].w, 0.f), acc.w);
            }
        }
    }

    float4 r;
    r.x = fmaf(scale, dv.x, acc.x);
    r.y = fmaf(scale, dv.y, acc.y);
    r.z = fmaf(scale, dv.z, acc.z);
    r.w = fmaf(scale, dv.w, acc.w);

    unsigned short h0 = (unsigned short)bf16rn(r.x);
    unsigned short h1 = (unsigned short)bf16rn(r.y);
    unsigned short h2 = (unsigned short)bf16rn(r.z);
    unsigned short h3 = (unsigned short)bf16rn(r.w);
    long o = ((long)z * KN + node) * KH + li * 4;
    *(uint2*)(agg_b + o) = make_uint2(((unsigned)h1 << 16) | h0,
                                      ((unsigned)h3 << 16) | h2);
}

// ---------------------------------------------------------------------------
// W pre-split: wsp[((mat*2+h)*4 + kc)*4096 + col*32 + kk], k = kc*32+kk.
// mat = arr*8 + (t*2+l), arr: 0=w1_ad 1=w1_da 2=w2_ad 3=w2_da.
// ---------------------------------------------------------------------------
__global__ __launch_bounds__(256)
void wsplit_k(const float* __restrict__ w1_ad, const float* __restrict__ w1_da,
              const float* __restrict__ w2_ad, const float* __restrict__ w2_da,
              short* __restrict__ wsp) {
    int mat = blockIdx.x >> 3, part = blockIdx.x & 7;   // mat 0..31
    int arr = mat >> 3, rem = mat & 7;   // rem = t*2+l
    const float* src = (arr == 0 ? w1_ad : arr == 1 ? w1_da : arr == 2 ? w2_ad : w2_da)
                       + (long)rem * KH * KH;
    #pragma unroll
    for (int p = 0; p < 8; ++p) {
        int idx = part * 2048 + p * 256 + threadIdx.x;  // 16384 elems total
        int k = idx >> 7, c = idx & 127;
        float v = src[idx];
        short hi = bf16rn(v);
        short lo = bf16rn(v - bf16tof(hi));
        int chunk = k >> 5, kk = k & 31;
        long ohi = ((long)(mat * 2 + 0) * 4 + chunk) * 4096 + c * 32 + kk;
        long olo = ((long)(mat * 2 + 1) * 4 + chunk) * 4096 + c * 32 + kk;
        wsp[ohi] = hi;
        wsp[olo] = lo;
    }
}

// ---------------------------------------------------------------------------
// Fused 2-layer MLP (2-term exact-A split MFMA, operand-swapped):
//   phase 1: mid = relu(agg @ (W1hi+W1lo) + b1), mid bf16 in LDS
//   phase 2: out = [relu](mid @ (W2hi+W2lo) + b2) -> d_out fp32
// A is single bf16 (exact input) -> 2 MFMAs per fragment, 33.8 KB LDS.
// Per (t,l) launch, blockIdx.y = et.
// ---------------------------------------------------------------------------
__global__ __launch_bounds__(256)
void fused_k(const short* __restrict__ agg_b,
             const short* __restrict__ wsp,
             const float* __restrict__ b1_ad, const float* __restrict__ b1_da,
             const float* __restrict__ b2_ad, const float* __restrict__ b2_da,
             float* __restrict__ d_out, int t, int l) {
    __shared__ short midh[128][132];    // 33.8 KB

    int et = blockIdx.y, z = t * 2 + et;
    int tid = threadIdx.x;
    int mat1 = (0 * 2 + et) * 8 + t * 2 + l;
    int mat2 = (1 * 2 + et) * 8 + t * 2 + l;
    const float* Bp1 = (et ? b1_da : b1_ad) + (long)(t * KL + l) * KH;
    const float* Bp2 = (et ? b2_da : b2_ad) + (long)(t * KL + l) * KH;
    int r0 = blockIdx.x * 128;

    int lane = tid & 63, wid = tid >> 6;
    int wr = wid >> 1, wc = wid & 1;
    int lrow = lane & 15, lq = lane >> 4;

    f32x4 acc[4][4];
    #pragma unroll
    for (int i = 0; i < 4; ++i)
        #pragma unroll
        for (int j = 0; j < 4; ++j) acc[i][j] = (f32x4){0.f, 0.f, 0.f, 0.f};

    // ---- phase 1: acc = agg @ W1 ----
    #pragma unroll
    for (int kc = 0; kc < 4; ++kc) {
        const short* whp = wsp + ((long)(mat1 * 2 + 0) * 4 + kc) * 4096;
        const short* wlp = wsp + ((long)(mat1 * 2 + 1) * 4 + kc) * 4096;
        short8v bhi[4], blo[4];
        #pragma unroll
        for (int j = 0; j < 4; ++j) {
            int off = (wc * 64 + j * 16 + lrow) * 32 + lq * 8;
            bhi[j] = *(const short8v*)(whp + off);
            blo[j] = *(const short8v*)(wlp + off);
        }
        #pragma unroll
        for (int i = 0; i < 4; ++i) {
            int row = min(r0 + wr * 64 + i * 16 + lrow, KN - 1);
            long o = ((long)z * KN + row) * KH + kc * 32 + lq * 8;
            short8v ahi = *(const short8v*)(agg_b + o);
            #pragma unroll
            for (int j = 0; j < 4; ++j) {
                acc[i][j] = __builtin_amdgcn_mfma_f32_16x16x32_bf16(bhi[j], ahi, acc[i][j], 0, 0, 0);
                acc[i][j] = __builtin_amdgcn_mfma_f32_16x16x32_bf16(blo[j], ahi, acc[i][j], 0, 0, 0);
            }
        }
    }

    // ---- epilogue 1: bias + relu -> bf16 -> LDS ----
    #pragma unroll
    for (int i = 0; i < 4; ++i) {
        int lr = wr * 64 + i * 16 + lrow;
        #pragma unroll
        for (int j = 0; j < 4; ++j) {
            int col = wc * 64 + j * 16 + lq * 4;
            float4 b4 = *(const float4*)&Bp1[col];
            f32x4 a = acc[i][j];
            float v0 = fmaxf(a[0] + b4.x, 0.f);
            float v1 = fmaxf(a[1] + b4.y, 0.f);
            float v2 = fmaxf(a[2] + b4.z, 0.f);
            float v3 = fmaxf(a[3] + b4.w, 0.f);
            unsigned short h0 = (unsigned short)bf16rn(v0);
            unsigned short h1 = (unsigned short)bf16rn(v1);
            unsigned short h2 = (unsigned short)bf16rn(v2);
            unsigned short h3 = (unsigned short)bf16rn(v3);
            *(uint2*)&midh[lr][col] = make_uint2(((unsigned)h1 << 16) | h0,
                                                 ((unsigned)h3 << 16) | h2);
        }
    }
    __syncthreads();

    // ---- phase 2: acc = mid @ W2 ----
    #pragma unroll
    for (int i = 0; i < 4; ++i)
        #pragma unroll
        for (int j = 0; j < 4; ++j) acc[i][j] = (f32x4){0.f, 0.f, 0.f, 0.f};

    #pragma unroll
    for (int kc = 0; kc < 4; ++kc) {
        const short* whp = wsp + ((long)(mat2 * 2 + 0) * 4 + kc) * 4096;
        const short* wlp = wsp + ((long)(mat2 * 2 + 1) * 4 + kc) * 4096;
        short8v bhi[4], blo[4];
        #pragma unroll
        for (int j = 0; j < 4; ++j) {
            int off = (wc * 64 + j * 16 + lrow) * 32 + lq * 8;
            bhi[j] = *(const short8v*)(whp + off);
            blo[j] = *(const short8v*)(wlp + off);
        }
        #pragma unroll
        for (int i = 0; i < 4; ++i) {
            int lr = wr * 64 + i * 16 + lrow;
            int co = kc * 32 + lq * 8;
            uint2 ha = *(const uint2*)&midh[lr][co];
            uint2 hb = *(const uint2*)&midh[lr][co + 4];
            short8v ahi = mk8(ha, hb);
            #pragma unroll
            for (int j = 0; j < 4; ++j) {
                acc[i][j] = __builtin_amdgcn_mfma_f32_16x16x32_bf16(bhi[j], ahi, acc[i][j], 0, 0, 0);
                acc[i][j] = __builtin_amdgcn_mfma_f32_16x16x32_bf16(blo[j], ahi, acc[i][j], 0, 0, 0);
            }
        }
    }

    // ---- epilogue 2: bias (+relu between layers), fp32 to d_out ----
    int relu = (l == 0) ? 1 : 0;
    #pragma unroll
    for (int i = 0; i < 4; ++i) {
        int node = r0 + wr * 64 + i * 16 + lrow;
        if (node >= KN) continue;
        #pragma unroll
        for (int j = 0; j < 4; ++j) {
            int col = wc * 64 + j * 16 + lq * 4;
            float4 b4 = *(const float4*)&Bp2[col];
            f32x4 a = acc[i][j];
            float4 v;
            v.x = a[0] + b4.x; v.y = a[1] + b4.y;
            v.z = a[2] + b4.z; v.w = a[3] + b4.w;
            if (relu) {
                v.x = fmaxf(v.x, 0.f); v.y = fmaxf(v.y, 0.f);
                v.z = fmaxf(v.z, 0.f); v.w = fmaxf(v.w, 0.f);
            }
            long off = (long)t * KNT * KH + (et == 0 ? (long)KN * KH : 0)
                     + (long)node * KH + col;
            *(float4*)&d_out[off] = v;
        }
    }
}

// ---------------------------------------------------------------------------
extern "C" void kernel_launch(void* const* d_in, const int* in_sizes, int n_in,
                              void* d_out_v, int out_size, void* d_ws, size_t ws_size,
                              hipStream_t stream) {
    const float* x_a    = (const float*)d_in[0];
    const float* x_d    = (const float*)d_in[1];
    const float* ea_ad  = (const float*)d_in[2];
    const float* ea_da  = (const float*)d_in[3];
    const int*   ei_ad  = (const int*)d_in[4];
    const int*   ei_da  = (const int*)d_in[5];
    const float* w1_ad  = (const float*)d_in[6];
    const float* b1_ad  = (const float*)d_in[7];
    const float* w2_ad  = (const float*)d_in[8];
    const float* b2_ad  = (const float*)d_in[9];
    const float* eps_ad = (const float*)d_in[10];
    const float* w1_da  = (const float*)d_in[11];
    const float* b1_da  = (const float*)d_in[12];
    const float* w2_da  = (const float*)d_in[13];
    const float* b2_da  = (const float*)d_in[14];
    const float* eps_da = (const float*)d_in[15];
    float* out = (float*)d_out_v;

    // workspace layout: agg_b | offs | cur | pes | wsp  (~52 MB)
    size_t nEl = (size_t)8 * KN * KH;
    short* agg_b = (short*)d_ws;
    int*   offs  = (int*)(agg_b + nEl);
    int*   cur   = offs + (size_t)8 * (KN + 1);
    int2*  pes   = (int2*)(cur + (size_t)8 * KN);
    short* wsp   = (short*)(pes + (size_t)8 * KE);       // 1,048,576 shorts

    hipMemsetAsync(cur, 0, (size_t)8 * KN * sizeof(int), stream);
    wsplit_k<<<256, 256, 0, stream>>>(w1_ad, w1_da, w2_ad, w2_da, wsp);

    dim3 eg((KE + 255) / 256, 8);
    count_k<<<eg, 256, 0, stream>>>(ei_ad, ei_da, cur);
    scan_k<<<8, 256, 0, stream>>>(cur, offs);
    fill_k<<<eg, 256, 0, stream>>>(ei_ad, ei_da, cur, pes);

    dim3 ag(KN / 8, 2);                  // 2500 x 2 (et)
    dim3 gg((KN + 127) / 128, 2);        // 157 x 2 (et)

    // per-timestep schedule: ea[t] (102 MB) stays L3-resident between the
    // l=0 and l=1 agg launches -> l=1 re-reads it from Infinity Cache.
    for (int t = 0; t < KT; ++t) {
        for (int l = 0; l < KL; ++l) {
            const float* xab; long xats;
            const float* xdb; long xdts;
            if (l == 0) {
                xab = x_a; xats = (long)KN * KH;
                xdb = x_d; xdts = (long)KN * KH;
            } else {
                xab = out;                 xats = (long)KNT * KH;
                xdb = out + (long)KN * KH; xdts = (long)KNT * KH;
            }
            agg_k<<<ag, 256, 0, stream>>>(xab, xats, xdb, xdts,
                                          ea_ad, ea_da, eps_ad, eps_da,
                                          offs, pes, agg_b, t, l);
            fused_k<<<gg, 256, 0, stream>>>(agg_b, wsp,
                                            b1_ad, b1_da, b2_ad, b2_da,
                                            out, t, l);
        }
    }
}

// Round 16
// 572.196 us; speedup vs baseline: 1.0329x; 1.0329x over previous
//
#include <hip/hip_runtime.h>

#define KT 4
#define KN 20000        // NA == ND == 20000
#define KE 100000
#define KH 128
#define KL 2
#define KNT 40000       // NA + ND

typedef __attribute__((ext_vector_type(8))) short short8v;
typedef __attribute__((ext_vector_type(4))) float f32x4;

__device__ __forceinline__ short bf16rn(float x) {
    unsigned u = __float_as_uint(x);
    u = (u + 0x7fffu + ((u >> 16) & 1u)) >> 16;
    return (short)u;
}
__device__ __forceinline__ float bf16tof(short h) {
    return __uint_as_float(((unsigned)(unsigned short)h) << 16);
}
__device__ __forceinline__ short8v mk8(uint2 a, uint2 b) {
    union { unsigned u[4]; short8v s; } c;
    c.u[0] = a.x; c.u[1] = a.y; c.u[2] = b.x; c.u[3] = b.y;
    return c.s;
}

// ---------------------------------------------------------------------------
// CSR build: counts -> scan -> fill (packed (edge, src) pairs).  All 8 z.
// ---------------------------------------------------------------------------
__global__ void count_k(const int* __restrict__ ei_ad, const int* __restrict__ ei_da,
                        int* __restrict__ cnt) {
    int e = blockIdx.x * 256 + threadIdx.x;
    int z = blockIdx.y;                 // z = t*2 + et
    if (e >= KE) return;
    int t = z >> 1, et = z & 1;
    const int* ei = et ? ei_da : ei_ad;
    int dst = ei[(t * 2 + 1) * KE + e];
    atomicAdd(&cnt[z * KN + dst], 1);
}

__global__ void scan_k(int* __restrict__ cnt, int* __restrict__ offs) {
    __shared__ int s[256];
    int z = blockIdx.x, tid = threadIdx.x;
    const int CH = (KN + 255) / 256;    // 79
    int n0 = tid * CH;
    int lim = n0 < KN ? min(CH, KN - n0) : 0;
    long base = (long)z * KN + n0;
    int sum = 0;
    for (int i = 0; i < lim; ++i) sum += cnt[base + i];
    s[tid] = sum;
    __syncthreads();
    for (int off = 1; off < 256; off <<= 1) {
        int v = (tid >= off) ? s[tid - off] : 0;
        __syncthreads();
        s[tid] += v;
        __syncthreads();
    }
    int run = s[tid] - sum;             // exclusive prefix
    for (int i = 0; i < lim; ++i) {
        int c = cnt[base + i];
        offs[(long)z * (KN + 1) + n0 + i] = run;
        cnt[base + i] = run;            // becomes fill cursor
        run += c;
    }
    if (tid == 0) offs[(long)z * (KN + 1) + KN] = KE;
}

__global__ void fill_k(const int* __restrict__ ei_ad, const int* __restrict__ ei_da,
                       int* __restrict__ cur, int2* __restrict__ pes) {
    int e = blockIdx.x * 256 + threadIdx.x;
    int z = blockIdx.y;
    if (e >= KE) return;
    int t = z >> 1, et = z & 1;
    const int* ei = et ? ei_da : ei_ad;
    int src = ei[(t * 2 + 0) * KE + e];
    int dst = ei[(t * 2 + 1) * KE + e];
    int pos = atomicAdd(&cur[z * KN + dst], 1);
    pes[(long)z * KE + pos] = make_int2(e, src);
}

// ---------------------------------------------------------------------------
// W pre-split: wsp[((mat*2+h)*4 + kc)*4096 + col*32 + kk], k = kc*32+kk.
// mat = arr*8 + (t*2+l), arr: 0=w1_ad 1=w1_da 2=w2_ad 3=w2_da.
// ---------------------------------------------------------------------------
__global__ __launch_bounds__(256)
void wsplit_k(const float* __restrict__ w1_ad, const float* __restrict__ w1_da,
              const float* __restrict__ w2_ad, const float* __restrict__ w2_da,
              short* __restrict__ wsp) {
    int mat = blockIdx.x >> 3, part = blockIdx.x & 7;   // mat 0..31
    int arr = mat >> 3, rem = mat & 7;   // rem = t*2+l
    const float* src = (arr == 0 ? w1_ad : arr == 1 ? w1_da : arr == 2 ? w2_ad : w2_da)
                       + (long)rem * KH * KH;
    #pragma unroll
    for (int p = 0; p < 8; ++p) {
        int idx = part * 2048 + p * 256 + threadIdx.x;  // 16384 elems total
        int k = idx >> 7, c = idx & 127;
        float v = src[idx];
        short hi = bf16rn(v);
        short lo = bf16rn(v - bf16tof(hi));
        int chunk = k >> 5, kk = k & 31;
        long ohi = ((long)(mat * 2 + 0) * 4 + chunk) * 4096 + c * 32 + kk;
        long olo = ((long)(mat * 2 + 1) * 4 + chunk) * 4096 + c * 32 + kk;
        wsp[ohi] = hi;
        wsp[olo] = lo;
    }
}

// ---------------------------------------------------------------------------
// Fully fused per-layer kernel: gather -> LDS -> 2-layer MLP -> lay_out.
// ALIASING DISCIPLINE: layer inputs and outputs are distinct buffers.
//   l=0: reads x_a/x_d (inputs),     writes x1 (workspace ping buffer)
//   l=1: reads x1,                   writes d_out
// (R15 bug: l=1 read and wrote d_out in one launch -> inter-block race.)
//   phase 0: block's 128 nodes gathered (proven 4-deep fp32 CSR loop) ->
//            bf16 tile aggT in LDS.  Co-resident blocks overlap gather with
//            MFMA phases.
//   phase 1: mid = relu(aggT @ (W1hi+W1lo) + b1) -> bf16 midT in LDS
//   phase 2: out = [relu](midT @ (W2hi+W2lo) + b2) -> lay_out fp32
// Block: 128 nodes x 128 cols, 4 waves.  LDS 67.6 KB -> 2 blocks/CU.
// ---------------------------------------------------------------------------
__global__ __launch_bounds__(256)
void fused_k(const float* __restrict__ xa, const float* __restrict__ xd,
             const float* __restrict__ lay_in,
             const float* __restrict__ ea_ad, const float* __restrict__ ea_da,
             const float* __restrict__ eps_ad, const float* __restrict__ eps_da,
             const int* __restrict__ offs, const int2* __restrict__ pes,
             const short* __restrict__ wsp,
             const float* __restrict__ b1_ad, const float* __restrict__ b1_da,
             const float* __restrict__ b2_ad, const float* __restrict__ b2_da,
             float* __restrict__ lay_out, int l) {
    __shared__ short aggT[128][132];    // 33.8 KB
    __shared__ short midT[128][132];    // 33.8 KB

    int z = blockIdx.y, t = z >> 1, et = z & 1;
    int tid = threadIdx.x;
    int r0 = blockIdx.x * 128;

    // ---- phase 0: gather this block's 128 nodes into aggT ----
    {
        const float* ea  = (et ? ea_da : ea_ad) + (long)t * KE * KH;
        const float* eps = et ? eps_da : eps_ad;
        const float *src, *dst;
        if (l == 0) {
            src = et ? (xd + (long)t * KN * KH) : (xa + (long)t * KN * KH);
            dst = et ? (xa + (long)t * KN * KH) : (xd + (long)t * KN * KH);
        } else {
            const float* base = lay_in + (long)t * KNT * KH;
            src = et ? (base + (long)KN * KH) : base;
            dst = et ? base : (base + (long)KN * KH);
        }
        float scale = 1.0f + eps[t * KL + l];
        const int2* pz = pes + (long)z * KE;
        int li = tid & 31, grp = tid >> 5;

        #pragma unroll 2
        for (int p = 0; p < 16; ++p) {
            int lr = p * 8 + grp;
            int node = r0 + lr;
            float4 r = make_float4(0.f, 0.f, 0.f, 0.f);
            if (node < KN) {
                float4 dv = *(const float4*)(dst + (long)node * KH + li * 4);
                float4 acc = make_float4(0.f, 0.f, 0.f, 0.f);
                int beg = offs[(long)z * (KN + 1) + node];
                int end = offs[(long)z * (KN + 1) + node + 1];
                if (beg < end) {
                    int last = end - 1;
                    for (int i = beg; i < end; i += 4) {
                        int i0 = min(i, last), i1 = min(i + 1, last),
                            i2 = min(i + 2, last), i3 = min(i + 3, last);
                        int2 p0 = pz[i0], p1 = pz[i1], p2 = pz[i2], p3 = pz[i3];
                        float4 e0 = *(const float4*)(ea + (long)p0.x * KH + li * 4);
                        float4 e1 = *(const float4*)(ea + (long)p1.x * KH + li * 4);
                        float4 e2 = *(const float4*)(ea + (long)p2.x * KH + li * 4);
                        float4 e3 = *(const float4*)(ea + (long)p3.x * KH + li * 4);
                        float4 x0 = *(const float4*)(src + (long)p0.y * KH + li * 4);
                        float4 x1v = *(const float4*)(src + (long)p1.y * KH + li * 4);
                        float4 x2 = *(const float4*)(src + (long)p2.y * KH + li * 4);
                        float4 x3 = *(const float4*)(src + (long)p3.y * KH + li * 4);
                        float4 es4[4] = {e0, e1, e2, e3};
                        float4 xs[4] = {x0, x1v, x2, x3};
                        #pragma unroll
                        for (int u = 0; u < 4; ++u) {
                            float m = (i + u <= last) ? 1.0f : 0.0f;
                            acc.x = fmaf(m, fmaxf(xs[u].x + es4[u].x, 0.f), acc.x);
                            acc.y = fmaf(m, fmaxf(xs[u].y + es4[u].y, 0.f), acc.y);
                            acc.z = fmaf(m, fmaxf(xs[u].z + es4[u].z, 0.f), acc.z);
                            acc.w = fmaf(m, fmaxf(xs[u].w + es4[u].w, 0.f), acc.w);
                        }
                    }
                }
                r.x = fmaf(scale, dv.x, acc.x);
                r.y = fmaf(scale, dv.y, acc.y);
                r.z = fmaf(scale, dv.z, acc.z);
                r.w = fmaf(scale, dv.w, acc.w);
            }
            unsigned short h0 = (unsigned short)bf16rn(r.x);
            unsigned short h1 = (unsigned short)bf16rn(r.y);
            unsigned short h2 = (unsigned short)bf16rn(r.z);
            unsigned short h3 = (unsigned short)bf16rn(r.w);
            *(uint2*)&aggT[lr][li * 4] = make_uint2(((unsigned)h1 << 16) | h0,
                                                    ((unsigned)h3 << 16) | h2);
        }
    }
    __syncthreads();

    int mat1 = (0 * 2 + et) * 8 + t * 2 + l;
    int mat2 = (1 * 2 + et) * 8 + t * 2 + l;
    const float* Bp1 = (et ? b1_da : b1_ad) + (long)(t * KL + l) * KH;
    const float* Bp2 = (et ? b2_da : b2_ad) + (long)(t * KL + l) * KH;

    int lane = tid & 63, wid = tid >> 6;
    int wr = wid >> 1, wc = wid & 1;
    int lrow = lane & 15, lq = lane >> 4;

    f32x4 acc[4][4];
    #pragma unroll
    for (int i = 0; i < 4; ++i)
        #pragma unroll
        for (int j = 0; j < 4; ++j) acc[i][j] = (f32x4){0.f, 0.f, 0.f, 0.f};

    // ---- phase 1: acc = aggT @ W1 ----
    #pragma unroll
    for (int kc = 0; kc < 4; ++kc) {
        const short* whp = wsp + ((long)(mat1 * 2 + 0) * 4 + kc) * 4096;
        const short* wlp = wsp + ((long)(mat1 * 2 + 1) * 4 + kc) * 4096;
        short8v bhi[4], blo[4];
        #pragma unroll
        for (int j = 0; j < 4; ++j) {
            int off = (wc * 64 + j * 16 + lrow) * 32 + lq * 8;
            bhi[j] = *(const short8v*)(whp + off);
            blo[j] = *(const short8v*)(wlp + off);
        }
        #pragma unroll
        for (int i = 0; i < 4; ++i) {
            int lr = wr * 64 + i * 16 + lrow;
            int co = kc * 32 + lq * 8;
            short8v ahi = mk8(*(const uint2*)&aggT[lr][co],
                              *(const uint2*)&aggT[lr][co + 4]);
            #pragma unroll
            for (int j = 0; j < 4; ++j) {
                acc[i][j] = __builtin_amdgcn_mfma_f32_16x16x32_bf16(bhi[j], ahi, acc[i][j], 0, 0, 0);
                acc[i][j] = __builtin_amdgcn_mfma_f32_16x16x32_bf16(blo[j], ahi, acc[i][j], 0, 0, 0);
            }
        }
    }

    // ---- epilogue 1: bias + relu -> bf16 -> midT ----
    #pragma unroll
    for (int i = 0; i < 4; ++i) {
        int lr = wr * 64 + i * 16 + lrow;
        #pragma unroll
        for (int j = 0; j < 4; ++j) {
            int col = wc * 64 + j * 16 + lq * 4;
            float4 b4 = *(const float4*)&Bp1[col];
            f32x4 a = acc[i][j];
            float v0 = fmaxf(a[0] + b4.x, 0.f);
            float v1 = fmaxf(a[1] + b4.y, 0.f);
            float v2 = fmaxf(a[2] + b4.z, 0.f);
            float v3 = fmaxf(a[3] + b4.w, 0.f);
            unsigned short h0 = (unsigned short)bf16rn(v0);
            unsigned short h1 = (unsigned short)bf16rn(v1);
            unsigned short h2 = (unsigned short)bf16rn(v2);
            unsigned short h3 = (unsigned short)bf16rn(v3);
            *(uint2*)&midT[lr][col] = make_uint2(((unsigned)h1 << 16) | h0,
                                                 ((unsigned)h3 << 16) | h2);
        }
    }
    __syncthreads();

    // ---- phase 2: acc = midT @ W2 ----
    #pragma unroll
    for (int i = 0; i < 4; ++i)
        #pragma unroll
        for (int j = 0; j < 4; ++j) acc[i][j] = (f32x4){0.f, 0.f, 0.f, 0.f};

    #pragma unroll
    for (int kc = 0; kc < 4; ++kc) {
        const short* whp = wsp + ((long)(mat2 * 2 + 0) * 4 + kc) * 4096;
        const short* wlp = wsp + ((long)(mat2 * 2 + 1) * 4 + kc) * 4096;
        short8v bhi[4], blo[4];
        #pragma unroll
        for (int j = 0; j < 4; ++j) {
            int off = (wc * 64 + j * 16 + lrow) * 32 + lq * 8;
            bhi[j] = *(const short8v*)(whp + off);
            blo[j] = *(const short8v*)(wlp + off);
        }
        #pragma unroll
        for (int i = 0; i < 4; ++i) {
            int lr = wr * 64 + i * 16 + lrow;
            int co = kc * 32 + lq * 8;
            short8v ahi = mk8(*(const uint2*)&midT[lr][co],
                              *(const uint2*)&midT[lr][co + 4]);
            #pragma unroll
            for (int j = 0; j < 4; ++j) {
                acc[i][j] = __builtin_amdgcn_mfma_f32_16x16x32_bf16(bhi[j], ahi, acc[i][j], 0, 0, 0);
                acc[i][j] = __builtin_amdgcn_mfma_f32_16x16x32_bf16(blo[j], ahi, acc[i][j], 0, 0, 0);
            }
        }
    }

    // ---- epilogue 2: bias (+relu between layers), fp32 to lay_out ----
    int relu = (l == 0) ? 1 : 0;
    #pragma unroll
    for (int i = 0; i < 4; ++i) {
        int node = r0 + wr * 64 + i * 16 + lrow;
        if (node >= KN) continue;
        #pragma unroll
        for (int j = 0; j < 4; ++j) {
            int col = wc * 64 + j * 16 + lq * 4;
            float4 b4 = *(const float4*)&Bp2[col];
            f32x4 a = acc[i][j];
            float4 v;
            v.x = a[0] + b4.x; v.y = a[1] + b4.y;
            v.z = a[2] + b4.z; v.w = a[3] + b4.w;
            if (relu) {
                v.x = fmaxf(v.x, 0.f); v.y = fmaxf(v.y, 0.f);
                v.z = fmaxf(v.z, 0.f); v.w = fmaxf(v.w, 0.f);
            }
            long off = (long)t * KNT * KH + (et == 0 ? (long)KN * KH : 0)
                     + (long)node * KH + col;
            *(float4*)&lay_out[off] = v;
        }
    }
}

// ---------------------------------------------------------------------------
extern "C" void kernel_launch(void* const* d_in, const int* in_sizes, int n_in,
                              void* d_out_v, int out_size, void* d_ws, size_t ws_size,
                              hipStream_t stream) {
    const float* x_a    = (const float*)d_in[0];
    const float* x_d    = (const float*)d_in[1];
    const float* ea_ad  = (const float*)d_in[2];
    const float* ea_da  = (const float*)d_in[3];
    const int*   ei_ad  = (const int*)d_in[4];
    const int*   ei_da  = (const int*)d_in[5];
    const float* w1_ad  = (const float*)d_in[6];
    const float* b1_ad  = (const float*)d_in[7];
    const float* w2_ad  = (const float*)d_in[8];
    const float* b2_ad  = (const float*)d_in[9];
    const float* eps_ad = (const float*)d_in[10];
    const float* w1_da  = (const float*)d_in[11];
    const float* b1_da  = (const float*)d_in[12];
    const float* w2_da  = (const float*)d_in[13];
    const float* b2_da  = (const float*)d_in[14];
    const float* eps_da = (const float*)d_in[15];
    float* out = (float*)d_out_v;

    // workspace layout: x1 ping buffer | offs | cur | pes | wsp  (~86.5 MB)
    float* x1   = (float*)d_ws;                          // KT*KNT*KH fp32
    int*   offs = (int*)(x1 + (size_t)KT * KNT * KH);
    int*   cur  = offs + (size_t)8 * (KN + 1);
    int2*  pes  = (int2*)(cur + (size_t)8 * KN);
    short* wsp  = (short*)(pes + (size_t)8 * KE);        // 1,048,576 shorts

    hipMemsetAsync(cur, 0, (size_t)8 * KN * sizeof(int), stream);
    wsplit_k<<<256, 256, 0, stream>>>(w1_ad, w1_da, w2_ad, w2_da, wsp);

    dim3 eg((KE + 255) / 256, 8);
    count_k<<<eg, 256, 0, stream>>>(ei_ad, ei_da, cur);
    scan_k<<<8, 256, 0, stream>>>(cur, offs);
    fill_k<<<eg, 256, 0, stream>>>(ei_ad, ei_da, cur, pes);

    dim3 gg((KN + 127) / 128, 8);        // 157 x 8
    // l=0: inputs -> x1 ;  l=1: x1 -> d_out   (no buffer is read and
    // written in the same launch -> no inter-block race)
    fused_k<<<gg, 256, 0, stream>>>(x_a, x_d, (const float*)x1,
                                    ea_ad, ea_da, eps_ad, eps_da,
                                    offs, pes, wsp,
                                    b1_ad, b1_da, b2_ad, b2_da, x1, 0);
    fused_k<<<gg, 256, 0, stream>>>(x_a, x_d, (const float*)x1,
                                    ea_ad, ea_da, eps_ad, eps_da,
                                    offs, pes, wsp,
                                    b1_ad, b1_da, b2_ad, b2_da, out, 1);
}